// Round 4
// baseline (86.159 us; speedup 1.0000x reference)
//
#include <hip/hip_runtime.h>
#include <hip/hip_bf16.h>

// Problem constants (fixed by the reference's setup_inputs):
//   B=8, M=8192, D=256, MAX_HOP=3; all f32.
#define B 8
#define M 8192
#define D 256
#define BM (B * M)           // 65536
#define BMD ((size_t)B * M * D)

// ---------------------------------------------------------------------------
// Fused hop kernel. Grid = BM/64 = 1024 blocks, 256 threads (4 waves).
// Block bid owns 64 consecutive rows of batch b = bid>>7.
//
// Prologue: u_eff[d] = query[d] + on0[d]/z0 (+ on1[d]/z1)   (deferred softmax
//           normalization from previous hops — no separate u buffer/kernel)
// Phase 1:  l[row] = gp * dot(st_h[row,:], u_eff)  for its 64 rows;
//           keeps w[row] = exp(l)*gp in LDS only.
// Phase 2:  (skipped on final hop) o~[b][d] += sum_row w[row]*st_next[row,d]
//           via atomicAdd; Z[b] += sum_row exp(l).
// Final hop instead writes logits (output 1) and per-block psum partials.
// No max-subtraction: |l| <~ 10, exp is safe in f32 (validated rounds 1-3).
// ---------------------------------------------------------------------------
__global__ __launch_bounds__(256) void hop_kernel(
    const float* __restrict__ st_h,     // [B][M][D] story slice for logits
    const float* __restrict__ st_next,  // slice for o_k (null on final hop)
    const float* __restrict__ query,    // [B][D]
    const float* __restrict__ gp,       // [B][M]
    const float* __restrict__ on0, const float* __restrict__ z0,  // hop-0 fold
    const float* __restrict__ on1, const float* __restrict__ z1,  // hop-1 fold
    float* __restrict__ onum_out,       // [B][D] unnormalized o_k accumulator
    float* __restrict__ z_out,          // [B]
    float* __restrict__ logits_out,     // final hop only
    float* __restrict__ psum_out)       // final hop only: [B*128] partials
{
    const int bid = blockIdx.x;
    const int b = bid >> 7;
    const int tid = threadIdx.x, lane = tid & 63, wv = tid >> 6;
    const long long grow0 = (long long)bid * 64;   // first global row

    __shared__ float uu[256];
    __shared__ float gpv[64];
    __shared__ float w[64];
    __shared__ float sred[4];
    __shared__ float sacc[4][256];

    // u_eff with deferred normalization folds
    float uq = query[b * 256 + tid];
    if (on0) uq += on0[b * 256 + tid] / z0[b];
    if (on1) uq += on1[b * 256 + tid] / z1[b];
    uu[tid] = uq;
    if (tid < 64) gpv[tid] = gp[grow0 + tid];
    __syncthreads();

    const float4 uf = reinterpret_cast<const float4*>(uu)[lane];

    // ---- phase 1: logits for rows wv*16 .. wv*16+15 ----
    const float4* s1 = reinterpret_cast<const float4*>(st_h + grow0 * D) + lane;
    float esum = 0.f;
    #pragma unroll
    for (int r = 0; r < 16; ++r) {
        const int row = (wv << 4) + r;
        float4 s = s1[(size_t)row * 64];
        float v = s.x * uf.x + s.y * uf.y + s.z * uf.z + s.w * uf.w;
        #pragma unroll
        for (int off = 32; off; off >>= 1) v += __shfl_xor(v, off, 64);
        if (lane == 0) {
            const float g = gpv[row];
            const float l = v * g;
            const float e = __expf(l);
            esum += e;
            w[row] = e * g;
            if (logits_out) logits_out[grow0 + row] = l;
        }
    }
    if (lane == 0) sred[wv] = esum;
    __syncthreads();

    if (st_next == nullptr) {           // final hop: stats only
        if (tid == 0) psum_out[bid] = sred[0] + sred[1] + sred[2] + sred[3];
        return;
    }

    // ---- phase 2: unnormalized o_k over the same 64 rows of st_next ----
    const float4* s2 = reinterpret_cast<const float4*>(st_next + grow0 * D) + lane;
    float4 acc = {0.f, 0.f, 0.f, 0.f};
    #pragma unroll
    for (int r = 0; r < 16; ++r) {
        const int row = (wv << 4) + r;
        float4 s = s2[(size_t)row * 64];
        const float ww = w[row];
        acc.x += ww * s.x; acc.y += ww * s.y; acc.z += ww * s.z; acc.w += ww * s.w;
    }
    reinterpret_cast<float4*>(&sacc[wv][0])[lane] = acc;
    __syncthreads();
    const float o = sacc[0][tid] + sacc[1][tid] + sacc[2][tid] + sacc[3][tid];
    atomicAdd(&onum_out[b * 256 + tid], o);
    if (tid == 0) atomicAdd(z_out + b, sred[0] + sred[1] + sred[2] + sred[3]);
}

// ---------------- final prob_soft ------------------------------------------
__global__ __launch_bounds__(256) void prob_kernel(
    const float* __restrict__ logits,  // [B][M]
    const float* __restrict__ psum,    // [B*128]
    float* __restrict__ prob)          // [B][M]
{
    const int tid = threadIdx.x;
    const int b = blockIdx.x >> 5;     // 32 blocks per b
    __shared__ float red[128];
    if (tid < 128) red[tid] = psum[b * 128 + tid];
    __syncthreads();
    for (int s = 64; s; s >>= 1) {
        if (tid < s) red[tid] += red[tid + s];
        __syncthreads();
    }
    const float inv = 1.f / red[0];
    const int i = blockIdx.x * 256 + tid;
    prob[i] = __expf(logits[i]) * inv;
}

extern "C" void kernel_launch(void* const* d_in, const int* in_sizes, int n_in,
                              void* d_out, int out_size, void* d_ws, size_t ws_size,
                              hipStream_t stream) {
    const float* query = (const float*)d_in[0];   // [B][D]
    const float* gp    = (const float*)d_in[1];   // [B][M]
    const float* story = (const float*)d_in[2];   // [4][B][M][D]

    float* out    = (float*)d_out;
    float* prob   = out;             // [B][M] (output 0)
    float* logits = out + BM;        // [B][M] (output 1)

    float* ws   = (float*)d_ws;
    float* on0  = ws;                // [B*D]  = 2048
    float* z0   = ws + 2048;         // [B]    = 8
    float* on1  = ws + 2048 + 8;     // [B*D]  = 2048
    float* z1   = ws + 4096 + 8;     // [B]    = 8
    float* psum = ws + 4104;         // [B*128]

    const float* st0 = story;
    const float* st1 = story + BMD;
    const float* st2 = story + 2 * BMD;

    // zero the accumulators (on0,z0,on1,z1 are contiguous: 4112 floats)
    hipMemsetAsync(ws, 0, 4112 * sizeof(float), stream);

    // hop 0: logits(st0, query) fused with o~0 over st1
    hop_kernel<<<BM / 64, 256, 0, stream>>>(st0, st1, query, gp,
                                            nullptr, nullptr, nullptr, nullptr,
                                            on0, z0, nullptr, nullptr);
    // hop 1: logits(st1, query + o~0/Z0) fused with o~1 over st2
    hop_kernel<<<BM / 64, 256, 0, stream>>>(st1, st2, query, gp,
                                            on0, z0, nullptr, nullptr,
                                            on1, z1, nullptr, nullptr);
    // hop 2: logits(st2, query + o~0/Z0 + o~1/Z1) -> outputs
    hop_kernel<<<BM / 64, 256, 0, stream>>>(st2, nullptr, query, gp,
                                            on0, z0, on1, z1,
                                            nullptr, nullptr, logits, psum);
    prob_kernel<<<BM / 256, 256, 0, stream>>>(logits, psum, prob);
}